// Round 6
// baseline (1037.272 us; speedup 1.0000x reference)
//
#include <hip/hip_runtime.h>
#include <cstdint>

typedef __bf16 bf16_t;
typedef __bf16 bf16x8 __attribute__((ext_vector_type(8)));
typedef float f32x4 __attribute__((ext_vector_type(4)));

#define AS1 __attribute__((address_space(1)))
#define AS3 __attribute__((address_space(3)))

__device__ __forceinline__ void gload_lds16(const bf16_t* g, bf16_t* l) {
    __builtin_amdgcn_global_load_lds((const AS1 void*)g, (AS3 void*)l, 16, 0, 0);
}
__device__ __forceinline__ f32x4 mfma_bf16(bf16x8 a, bf16x8 b, f32x4 c) {
    return __builtin_amdgcn_mfma_f32_16x16x32_bf16(a, b, c, 0, 0, 0);
}

// ---------------------------------------------------------------------------
// 128x128-tile GEMM (attention-side: QK^T, PV).  256 thr = 4 waves (2x2),
// 32 KB LDS (SPLIT) -> 5 blocks/CU: barrier stalls filled by cross-block TLP
// (this exact structure benched best-total in round 1).  XCD swizzle added
// (FETCH 147->49 MB on comparable shapes, round 3).
// LDS 16B-slot swizzle phys = slot ^ ((row>>1)&3) on BOTH sides: 0 bank
// conflicts (verified rounds 1-5).
// ---------------------------------------------------------------------------
template <bool SPLIT, int BIAS, int OUTMODE>
__global__ __launch_bounds__(256) void gemm_bt(
    const bf16_t* __restrict__ Ah, const bf16_t* __restrict__ Al, long long strideA, int lda,
    const bf16_t* __restrict__ Bh, const bf16_t* __restrict__ Bl, long long strideB, int ldb,
    void* __restrict__ C0, void* __restrict__ C1, long long strideC, int ldc,
    const float* __restrict__ bias, int K)
{
    __shared__ bf16_t Ash[128 * 32];
    __shared__ bf16_t Bsh[128 * 32];
    __shared__ bf16_t Asl[SPLIT ? 128 * 32 : 8];
    __shared__ bf16_t Bsl[SPLIT ? 128 * 32 : 8];

    // XCD-aware swizzle (bijective when nwg%8==0, identity otherwise).
    int bx = blockIdx.x, by = blockIdx.y, bz = blockIdx.z;
    {
        const int gx = gridDim.x, gy = gridDim.y, gz = gridDim.z;
        const int n = gx * gy * gz;
        if ((n & 7) == 0) {
            int lin = bx + gx * (by + gy * bz);
            lin = (lin & 7) * (n >> 3) + (lin >> 3);
            bx = lin % gx; lin /= gx;
            by = lin % gy; bz = lin / gy;
        }
    }

    const int rowBase = by * 128;
    const int colBase = bx * 128;
    const bf16_t* AhB = Ah + (long long)bz * strideA;
    const bf16_t* BhB = Bh + (long long)bz * strideB;
    const bf16_t* AlB = SPLIT ? Al + (long long)bz * strideA : nullptr;
    const bf16_t* BlB = SPLIT ? Bl + (long long)bz * strideB : nullptr;

    const int t = threadIdx.x;
    const int lane = t & 63;
    const int w = t >> 6;
    const int wr = (w >> 1) * 64;
    const int wc = (w & 1) * 64;

    f32x4 acc[4][4] = {};

    const int r0 = t >> 2;                                   // staging row
    const int kc0 = (((t & 3) ^ ((r0 >> 1) & 3)) * 8);       // pre-swizzled src slot

    for (int k0 = 0; k0 < K; k0 += 32) {
        const long long aoff0 = (long long)(rowBase + r0) * lda + k0 + kc0;
        const long long aoff1 = (long long)(rowBase + r0 + 64) * lda + k0 + kc0;
        const long long boff0 = (long long)(colBase + r0) * ldb + k0 + kc0;
        const long long boff1 = (long long)(colBase + r0 + 64) * ldb + k0 + kc0;
        gload_lds16(AhB + aoff0, &Ash[t * 8]);
        gload_lds16(AhB + aoff1, &Ash[(t + 256) * 8]);
        gload_lds16(BhB + boff0, &Bsh[t * 8]);
        gload_lds16(BhB + boff1, &Bsh[(t + 256) * 8]);
        if (SPLIT) {
            gload_lds16(AlB + aoff0, &Asl[t * 8]);
            gload_lds16(AlB + aoff1, &Asl[(t + 256) * 8]);
            gload_lds16(BlB + boff0, &Bsl[t * 8]);
            gload_lds16(BlB + boff1, &Bsl[(t + 256) * 8]);
        }
        __syncthreads();

        const int fr = lane & 15;
        const int kqs = (((lane >> 4) ^ ((lane >> 1) & 3)) * 8);   // swizzled read
        bf16x8 ah[4], bh[4], al[4], bl[4];
#pragma unroll
        for (int mi = 0; mi < 4; mi++) {
            ah[mi] = *(const bf16x8*)&Ash[(wr + mi * 16 + fr) * 32 + kqs];
            if (SPLIT) al[mi] = *(const bf16x8*)&Asl[(wr + mi * 16 + fr) * 32 + kqs];
        }
#pragma unroll
        for (int ni = 0; ni < 4; ni++) {
            bh[ni] = *(const bf16x8*)&Bsh[(wc + ni * 16 + fr) * 32 + kqs];
            if (SPLIT) bl[ni] = *(const bf16x8*)&Bsl[(wc + ni * 16 + fr) * 32 + kqs];
        }

#pragma unroll
        for (int mi = 0; mi < 4; mi++)
#pragma unroll
            for (int ni = 0; ni < 4; ni++) {
                if (SPLIT) {
                    acc[mi][ni] = mfma_bf16(al[mi], bh[ni], acc[mi][ni]);
                    acc[mi][ni] = mfma_bf16(ah[mi], bl[ni], acc[mi][ni]);
                }
                acc[mi][ni] = mfma_bf16(ah[mi], bh[ni], acc[mi][ni]);
            }
        __syncthreads();
    }

    // epilogue: C/D layout col = lane&15, row = (lane>>4)*4 + reg
    const int fc = lane & 15;
    const int fr4 = (lane >> 4) * 4;
#pragma unroll
    for (int mi = 0; mi < 4; mi++)
#pragma unroll
        for (int ni = 0; ni < 4; ni++)
#pragma unroll
            for (int rg = 0; rg < 4; rg++) {
                const int row = rowBase + wr + mi * 16 + fr4 + rg;
                const int col = colBase + wc + ni * 16 + fc;
                float v = acc[mi][ni][rg];
                if (BIAS == 1) v += bias[col];
                else if (BIAS == 2) v += bias[row];
                const long long off = (long long)bz * strideC + (long long)row * ldc + col;
                if (OUTMODE == 0) {
                    ((float*)C0)[off] = v;
                } else if (OUTMODE == 1) {
                    ((bf16_t*)C0)[off] = (bf16_t)v;
                } else {
                    const bf16_t h = (bf16_t)v;
                    ((bf16_t*)C0)[off] = h;
                    ((bf16_t*)C1)[off] = (bf16_t)(v - (float)h);
                }
            }
}

// ---------------------------------------------------------------------------
// 256x256-tile GEMM (projection-side).  512 thr = 8 waves (2Mx4N), per-wave
// 128x64.  4-deep LDS ring (128 KB), tile j+3 staged while computing j; one
// counted vmcnt(8) + raw s_barrier per tile (never drains mid-loop).
// Measured 103 us / MfmaUtil 43% on the split Q-proj (round 5).
// OUTMODE: 0 fp32; 1 bf16; 2 split(hi->C0,lo->C1);
//          3 bf16 transposed: C0[zb*strideC + col*ldc + (row%zrows)] via
//            aligned ushort4 (V^T epilogue).
// ---------------------------------------------------------------------------
template <bool SPLIT, int BIAS, int OUTMODE>
__global__ __launch_bounds__(512, 2) void gemm256(
    const bf16_t* __restrict__ Ah, const bf16_t* __restrict__ Al, long long strideA, int lda,
    const bf16_t* __restrict__ Bh, const bf16_t* __restrict__ Bl, long long strideB, int ldb,
    void* __restrict__ C0, void* __restrict__ C1, long long strideC, int ldc,
    const float* __restrict__ bias, int K, int zrows)
{
    __shared__ bf16_t lds[4 * 16384];   // 4 ring buffers: [A 256x32 | B 256x32]

    int bx = blockIdx.x, by = blockIdx.y, bz = blockIdx.z;
    {
        const int gx = gridDim.x, gy = gridDim.y, gz = gridDim.z;
        const int n = gx * gy * gz;
        if ((n & 7) == 0) {
            int lin = bx + gx * (by + gy * bz);
            lin = (lin & 7) * (n >> 3) + (lin >> 3);
            bx = lin % gx; lin /= gx;
            by = lin % gy; bz = lin / gy;
        }
    }

    const int rowBase = by * 256;
    const int colBase = bx * 256;
    const bf16_t* AhB = Ah + (long long)bz * strideA;
    const bf16_t* BhB = Bh + (long long)bz * strideB;
    const bf16_t* AlB = SPLIT ? Al + (long long)bz * strideA : nullptr;
    const bf16_t* BlB = SPLIT ? Bl + (long long)bz * strideB : nullptr;

    const int t = threadIdx.x;
    const int lane = t & 63;
    const int w = t >> 6;
    const int wm = w >> 2;
    const int wn = w & 3;

    const int r0 = t >> 2;
    const int sl8 = ((t & 3) ^ ((r0 >> 1) & 3)) * 8;
    const long long aoff0 = (long long)(rowBase + r0) * lda + sl8;
    const long long aoff1 = (long long)(rowBase + r0 + 128) * lda + sl8;
    const long long boff0 = (long long)(colBase + r0) * ldb + sl8;
    const long long boff1 = (long long)(colBase + r0 + 128) * ldb + sl8;

    const int NT = SPLIT ? (K >> 5) * 3 : (K >> 5);

    auto tsrc = [&](int jt, const bf16_t*& sA, const bf16_t*& sB, long long& k0) {
        if (SPLIT) {
            const int chunk = jt / 3;
            const int term = jt - chunk * 3;
            k0 = (long long)chunk * 32;
            sA = (term == 2) ? AlB : AhB;
            sB = (term == 1) ? BlB : BhB;
        } else {
            k0 = (long long)jt * 32;
            sA = AhB; sB = BhB;
        }
    };

    auto stage = [&](int jt) {
        const bf16_t *sA, *sB; long long k0;
        tsrc(jt, sA, sB, k0);
        bf16_t* db = lds + (jt & 3) * 16384;
        gload_lds16(sA + aoff0 + k0, db + t * 8);
        gload_lds16(sA + aoff1 + k0, db + 4096 + t * 8);
        gload_lds16(sB + boff0 + k0, db + 8192 + t * 8);
        gload_lds16(sB + boff1 + k0, db + 12288 + t * 8);
    };

    f32x4 acc[8][4] = {};

    stage(0); stage(1); stage(2);
    asm volatile("s_waitcnt vmcnt(8)" ::: "memory");
    __builtin_amdgcn_s_barrier();

    const int fr = lane & 15;
    const int kqs = ((lane >> 4) ^ ((lane >> 1) & 3)) * 8;

    for (int j = 0; j < NT; ++j) {
        const bf16_t* bufA = lds + (j & 3) * 16384;
        const bf16_t* bufB = bufA + 8192;

        if (j + 3 < NT) stage(j + 3);

        bf16x8 a[8], b[4];
#pragma unroll
        for (int mi = 0; mi < 8; mi++)
            a[mi] = *(const bf16x8*)&bufA[(wm * 128 + mi * 16 + fr) * 32 + kqs];
#pragma unroll
        for (int ni = 0; ni < 4; ni++)
            b[ni] = *(const bf16x8*)&bufB[(wn * 64 + ni * 16 + fr) * 32 + kqs];

#pragma unroll
        for (int mi = 0; mi < 8; mi++)
#pragma unroll
            for (int ni = 0; ni < 4; ni++)
                acc[mi][ni] = mfma_bf16(a[mi], b[ni], acc[mi][ni]);

        if (j + 1 < NT) {
            if (j < NT - 3)       asm volatile("s_waitcnt vmcnt(8)" ::: "memory");
            else if (j == NT - 3) asm volatile("s_waitcnt vmcnt(4)" ::: "memory");
            else                  asm volatile("s_waitcnt vmcnt(0)" ::: "memory");
            __builtin_amdgcn_s_barrier();
        }
    }

    const int fc = lane & 15;
    const int fr4 = (lane >> 4) * 4;

    if (OUTMODE == 3) {
        const int zb = rowBase / zrows;
        const int mBase = rowBase - zb * zrows;
#pragma unroll
        for (int mi = 0; mi < 8; mi++)
#pragma unroll
            for (int ni = 0; ni < 4; ni++) {
                const int m0 = mBase + wm * 128 + mi * 16 + fr4;
                const int col = colBase + wn * 64 + ni * 16 + fc;
                bf16_t q[4];
#pragma unroll
                for (int rg = 0; rg < 4; rg++) {
                    float v = acc[mi][ni][rg];
                    if (BIAS == 1) v += bias[col];
                    q[rg] = (bf16_t)v;
                }
                const long long off = (long long)zb * strideC + (long long)col * ldc + m0;
                *(ushort4*)&((bf16_t*)C0)[off] = *(const ushort4*)q;
            }
        return;
    }

#pragma unroll
    for (int mi = 0; mi < 8; mi++)
#pragma unroll
        for (int ni = 0; ni < 4; ni++)
#pragma unroll
            for (int rg = 0; rg < 4; rg++) {
                const int row = rowBase + wm * 128 + mi * 16 + fr4 + rg;
                const int col = colBase + wn * 64 + ni * 16 + fc;
                float v = acc[mi][ni][rg];
                if (BIAS == 1) v += bias[col];
                else if (BIAS == 2) v += bias[row];
                const long long off = (long long)bz * strideC + (long long)row * ldc + col;
                if (OUTMODE == 0) {
                    ((float*)C0)[off] = v;
                } else if (OUTMODE == 1) {
                    ((bf16_t*)C0)[off] = (bf16_t)v;
                } else {
                    const bf16_t h = (bf16_t)v;
                    ((bf16_t*)C0)[off] = h;
                    ((bf16_t*)C1)[off] = (bf16_t)(v - (float)h);
                }
            }
}

// fp32 -> (hi, lo) bf16 split; n multiple of 1024; grid = n/1024 blocks of 256.
__global__ __launch_bounds__(256) void split_f32(const float* __restrict__ x,
                                                 bf16_t* __restrict__ h,
                                                 bf16_t* __restrict__ l)
{
    const long long i = ((long long)blockIdx.x * 256 + threadIdx.x) * 4;
    const float4 v = *(const float4*)&x[i];
    bf16_t hh[4], ll[4];
    const float vv[4] = {v.x, v.y, v.z, v.w};
#pragma unroll
    for (int j = 0; j < 4; j++) {
        hh[j] = (bf16_t)vv[j];
        ll[j] = (bf16_t)(vv[j] - (float)hh[j]);
    }
    *(short4*)&h[i] = *(short4*)hh;
    *(short4*)&l[i] = *(short4*)ll;
}

// fp32 -> bf16 cast; n multiple of 1024; grid = n/1024.
__global__ __launch_bounds__(256) void cast_f32(const float* __restrict__ x,
                                                bf16_t* __restrict__ y)
{
    const long long i = ((long long)blockIdx.x * 256 + threadIdx.x) * 4;
    const float4 v = *(const float4*)&x[i];
    bf16_t hh[4] = {(bf16_t)v.x, (bf16_t)v.y, (bf16_t)v.z, (bf16_t)v.w};
    *(short4*)&y[i] = *(short4*)hh;
}

// all weight conversions in one dispatch: y=0 split Wq, y=1 split Wk, y=2 cast Wv
__global__ __launch_bounds__(256) void prep_weights(
    const float* __restrict__ Wq, const float* __restrict__ Wk, const float* __restrict__ Wv,
    bf16_t* __restrict__ WqH, bf16_t* __restrict__ WqL,
    bf16_t* __restrict__ WkH, bf16_t* __restrict__ WkL, bf16_t* __restrict__ WvB)
{
    const long long i = ((long long)blockIdx.x * 256 + threadIdx.x) * 4;
    const int sel = blockIdx.y;
    const float* x = (sel == 0) ? Wq : (sel == 1) ? Wk : Wv;
    const float4 v = *(const float4*)&x[i];
    const float vv[4] = {v.x, v.y, v.z, v.w};
    bf16_t hh[4], ll[4];
#pragma unroll
    for (int j = 0; j < 4; j++) {
        hh[j] = (bf16_t)vv[j];
        ll[j] = (bf16_t)(vv[j] - (float)hh[j]);
    }
    if (sel == 0) { *(short4*)&WqH[i] = *(short4*)hh; *(short4*)&WqL[i] = *(short4*)ll; }
    else if (sel == 1) { *(short4*)&WkH[i] = *(short4*)hh; *(short4*)&WkL[i] = *(short4*)ll; }
    else { *(short4*)&WvB[i] = *(short4*)hh; }
}

// Row softmax with mask; S fp32 [rows][2048] -> P bf16 [rows][2048].
// mask row = n0 + (r & 2047).
__global__ __launch_bounds__(256) void softmax_rows(const float* __restrict__ S,
                                                    bf16_t* __restrict__ P,
                                                    const int* __restrict__ mask,
                                                    int n0)
{
    __shared__ float red[4];
    const long long r = blockIdx.x;
    const float* row = S + r * 2048;
    const int* mrow = mask + (long long)(n0 + (int)(r & 2047)) * 2048;
    const int t = threadIdx.x;

    float v[8];
#pragma unroll
    for (int i = 0; i < 8; i++) {
        const int j = i * 256 + t;
        v[i] = (mrow[j] != 0) ? row[j] : -1000000000.0f;
    }
    float m = v[0];
#pragma unroll
    for (int i = 1; i < 8; i++) m = fmaxf(m, v[i]);
#pragma unroll
    for (int off = 32; off; off >>= 1) m = fmaxf(m, __shfl_xor(m, off));
    if ((t & 63) == 0) red[t >> 6] = m;
    __syncthreads();
    const float rowmax = fmaxf(fmaxf(red[0], red[1]), fmaxf(red[2], red[3]));
    __syncthreads();

    float sum = 0.0f;
    float e[8];
#pragma unroll
    for (int i = 0; i < 8; i++) { e[i] = __expf(v[i] - rowmax); sum += e[i]; }
#pragma unroll
    for (int off = 32; off; off >>= 1) sum += __shfl_xor(sum, off);
    if ((t & 63) == 0) red[t >> 6] = sum;
    __syncthreads();
    const float inv = 1.0f / (red[0] + red[1] + red[2] + red[3]);

    bf16_t* prow = P + r * 2048;
#pragma unroll
    for (int i = 0; i < 8; i++) prow[i * 256 + t] = (bf16_t)(e[i] * inv);
}

extern "C" void kernel_launch(void* const* d_in, const int* in_sizes, int n_in,
                              void* d_out, int out_size, void* d_ws, size_t ws_size,
                              hipStream_t stream) {
    constexpr int Bb = 8, N = 2048, M = 2048, D = 1024;
    constexpr long long MB = 1LL << 20;

    const float* querys = (const float*)d_in[0];
    const float* keys   = (const float*)d_in[1];
    const float* values = (const float*)d_in[2];
    const int*   mask   = (const int*)d_in[3];
    const float* Wq = (const float*)d_in[4];
    const float* bq = (const float*)d_in[5];
    const float* Wk = (const float*)d_in[6];
    const float* bk = (const float*)d_in[7];
    const float* Wv = (const float*)d_in[8];
    const float* bv = (const float*)d_in[9];
    float* out = (float*)d_out;

    // ---- adaptive plan ----
    const long long w = (long long)ws_size;
    auto needB = [&](long long cb) { return 10 * MB + cb * 52 * MB; };
    int CB = 0;
    if      (w >= needB(8)) CB = 8;
    else if (w >= needB(4)) CB = 4;
    else if (w >= needB(2)) CB = 2;
    else if (w >= needB(1)) CB = 1;
    const bool batched = (CB != 0);
    int NCH = N;
    if (!batched) {
        CB = 1;
        NCH = (w >= 38 * MB + 512 * 2048 * 6) ? 512 : 256;
    }

    char* ws = (char*)d_ws;
    long long o = 0;
    auto carve = [&](long long bytes) { char* p = ws + o; o += bytes; return p; };
    bf16_t* WqH = (bf16_t*)carve(2 * MB);
    bf16_t* WqL = (bf16_t*)carve(2 * MB);
    bf16_t* WkH = (bf16_t*)carve(2 * MB);
    bf16_t* WkL = (bf16_t*)carve(2 * MB);
    bf16_t* WvB = (bf16_t*)carve(2 * MB);
    bf16_t* XH  = (bf16_t*)carve((long long)CB * 4 * MB);  // also reused as V staging
    bf16_t* XL  = (bf16_t*)carve((long long)CB * 4 * MB);
    bf16_t* QH  = (bf16_t*)carve((long long)CB * 4 * MB);
    bf16_t* QL  = (bf16_t*)carve((long long)CB * 4 * MB);
    bf16_t* KH  = (bf16_t*)carve((long long)CB * 4 * MB);
    bf16_t* KL  = (bf16_t*)carve((long long)CB * 4 * MB);
    bf16_t* VT  = (bf16_t*)carve((long long)CB * 4 * MB);  // [CB][D][M]
    float*  S   = (float*)carve(batched ? (long long)CB * N * M * 4 : (long long)NCH * 2048 * 4);
    bf16_t* P   = (bf16_t*)carve(batched ? (long long)CB * N * M * 2 : (long long)NCH * 2048 * 2);

    dim3 blk(256), blkG(512);
    const long long grpElems = (long long)CB * N * D;

    // weight conversions (once, single dispatch)
    prep_weights<<<dim3((D * D) / 1024, 3), blk, 0, stream>>>(
        Wq, Wk, Wv, WqH, WqL, WkH, WkL, WvB);

    for (int b0 = 0; b0 < Bb; b0 += CB) {
        const long long xoff = (long long)b0 * N * D;
        // q = xq @ Wq^T + bq -> split (rows = CB*N)  [256-tile kernel]
        split_f32<<<dim3(grpElems / 1024), blk, 0, stream>>>(querys + xoff, XH, XL);
        gemm256<true, 1, 2><<<dim3(D / 256, CB * N / 256, 1), blkG, 0, stream>>>(
            XH, XL, 0, D, WqH, WqL, 0, D, QH, QL, 0, D, bq, D, 1);
        // k = xk @ Wk^T + bk -> split
        split_f32<<<dim3(grpElems / 1024), blk, 0, stream>>>(keys + xoff, XH, XL);
        gemm256<true, 1, 2><<<dim3(D / 256, CB * M / 256, 1), blkG, 0, stream>>>(
            XH, XL, 0, D, WkH, WkL, 0, D, KH, KL, 0, D, bk, D, 1);
        // v = xv @ Wv^T + bv, written TRANSPOSED into VT[z][d][m]
        cast_f32<<<dim3(grpElems / 1024), blk, 0, stream>>>(values + xoff, XH);
        gemm256<false, 1, 3><<<dim3(D / 256, CB * M / 256, 1), blkG, 0, stream>>>(
            XH, nullptr, 0, D, WvB, nullptr, 0, D,
            VT, nullptr, (long long)D * M, M, bv, D, M);

        if (batched) {
            // S[z][n][m] = q[z][n] . k[z][m]  (fp32, split)  [128-tile kernel,
            // grid = 16x16xCB -> 5 blocks/CU TLP]
            gemm_bt<true, 0, 0><<<dim3(M / 128, N / 128, CB), blk, 0, stream>>>(
                QH, QL, (long long)N * D, D,
                KH, KL, (long long)M * D, D,
                S, nullptr, (long long)N * M, M, nullptr, D);
            softmax_rows<<<dim3(CB * N), blk, 0, stream>>>(S, P, mask, 0);
            // out[z][n][d] = sum_m P[z][n][m] * vT[z][d][m]  [128-tile kernel]
            gemm_bt<false, 0, 0><<<dim3(D / 128, N / 128, CB), blk, 0, stream>>>(
                P, nullptr, (long long)N * M, M,
                VT, nullptr, (long long)D * M, M,
                out + xoff, nullptr, (long long)N * D, D, nullptr, M);
        } else {
            for (int z = 0; z < CB; z++) {
                for (int n0 = 0; n0 < N; n0 += NCH) {
                    gemm_bt<true, 0, 0><<<dim3(M / 128, NCH / 128, 1), blk, 0, stream>>>(
                        QH + ((long long)z * N + n0) * D, QL + ((long long)z * N + n0) * D, 0, D,
                        KH + (long long)z * M * D, KL + (long long)z * M * D, 0, D,
                        S, nullptr, 0, M, nullptr, D);
                    softmax_rows<<<dim3(NCH), blk, 0, stream>>>(S, P, mask, n0);
                    gemm_bt<false, 0, 0><<<dim3(D / 128, NCH / 128, 1), blk, 0, stream>>>(
                        P, nullptr, 0, M, VT + (long long)z * D * M, nullptr, 0, M,
                        out + ((long long)(b0 + z) * N + n0) * D, nullptr, 0, D, nullptr, M);
                }
            }
        }
    }
    (void)in_sizes; (void)n_in; (void)out_size;
}

// Round 7
// 1007.011 us; speedup vs baseline: 1.0301x; 1.0301x over previous
//
#include <hip/hip_runtime.h>
#include <cstdint>

typedef __bf16 bf16_t;
typedef __bf16 bf16x8 __attribute__((ext_vector_type(8)));
typedef float f32x4 __attribute__((ext_vector_type(4)));

#define AS1 __attribute__((address_space(1)))
#define AS3 __attribute__((address_space(3)))

__device__ __forceinline__ void gload_lds16(const bf16_t* g, bf16_t* l) {
    __builtin_amdgcn_global_load_lds((const AS1 void*)g, (AS3 void*)l, 16, 0, 0);
}
__device__ __forceinline__ f32x4 mfma_bf16(bf16x8 a, bf16x8 b, f32x4 c) {
    return __builtin_amdgcn_mfma_f32_16x16x32_bf16(a, b, c, 0, 0, 0);
}

// ---------------------------------------------------------------------------
// 256x256-tile GEMM.  512 thr = 8 waves (2Mx4N), per-wave 128x64.
// 4-deep LDS ring (128 KB), tile j+3 staged while computing j; one counted
// vmcnt(8) + raw s_barrier per tile (never drains mid-loop).
// Measured: 103 us / MfmaUtil 43% split Q-proj; QK^T & PV both <103 us (R5).
// LDS 16B-slot swizzle phys = slot ^ ((row>>1)&3) on BOTH sides: 0 bank
// conflicts (verified rounds 1-6).  XCD-aware bijective block swizzle:
// FETCH 147->49 MB (round 3).
// SPLIT: logical K' = 3K; term 0: Ah*Bh, 1: Ah*Bl, 2: Al*Bh.
// BIAS: 0=none, 1=+bias[col], 2=+bias[row].
// OUTMODE: 0 fp32; 1 bf16; 2 split(hi->C0,lo->C1);
//          3 bf16 transposed: C0[zb*strideC + col*ldc + (row%zrows)] via
//            aligned ushort4 (V^T epilogue).
// ---------------------------------------------------------------------------
template <bool SPLIT, int BIAS, int OUTMODE>
__global__ __launch_bounds__(512, 2) void gemm256(
    const bf16_t* __restrict__ Ah, const bf16_t* __restrict__ Al, long long strideA, int lda,
    const bf16_t* __restrict__ Bh, const bf16_t* __restrict__ Bl, long long strideB, int ldb,
    void* __restrict__ C0, void* __restrict__ C1, long long strideC, int ldc,
    const float* __restrict__ bias, int K, int zrows)
{
    __shared__ bf16_t lds[4 * 16384];   // 4 ring buffers: [A 256x32 | B 256x32]

    int bx = blockIdx.x, by = blockIdx.y, bz = blockIdx.z;
    {
        const int gx = gridDim.x, gy = gridDim.y, gz = gridDim.z;
        const int n = gx * gy * gz;
        if ((n & 7) == 0) {
            int lin = bx + gx * (by + gy * bz);
            lin = (lin & 7) * (n >> 3) + (lin >> 3);
            bx = lin % gx; lin /= gx;
            by = lin % gy; bz = lin / gy;
        }
    }

    const int rowBase = by * 256;
    const int colBase = bx * 256;
    const bf16_t* AhB = Ah + (long long)bz * strideA;
    const bf16_t* BhB = Bh + (long long)bz * strideB;
    const bf16_t* AlB = SPLIT ? Al + (long long)bz * strideA : nullptr;
    const bf16_t* BlB = SPLIT ? Bl + (long long)bz * strideB : nullptr;

    const int t = threadIdx.x;
    const int lane = t & 63;
    const int w = t >> 6;
    const int wm = w >> 2;
    const int wn = w & 3;

    const int r0 = t >> 2;
    const int sl8 = ((t & 3) ^ ((r0 >> 1) & 3)) * 8;
    const long long aoff0 = (long long)(rowBase + r0) * lda + sl8;
    const long long aoff1 = (long long)(rowBase + r0 + 128) * lda + sl8;
    const long long boff0 = (long long)(colBase + r0) * ldb + sl8;
    const long long boff1 = (long long)(colBase + r0 + 128) * ldb + sl8;

    const int NT = SPLIT ? (K >> 5) * 3 : (K >> 5);

    auto tsrc = [&](int jt, const bf16_t*& sA, const bf16_t*& sB, long long& k0) {
        if (SPLIT) {
            const int chunk = jt / 3;
            const int term = jt - chunk * 3;
            k0 = (long long)chunk * 32;
            sA = (term == 2) ? AlB : AhB;
            sB = (term == 1) ? BlB : BhB;
        } else {
            k0 = (long long)jt * 32;
            sA = AhB; sB = BhB;
        }
    };

    auto stage = [&](int jt) {
        const bf16_t *sA, *sB; long long k0;
        tsrc(jt, sA, sB, k0);
        bf16_t* db = lds + (jt & 3) * 16384;
        gload_lds16(sA + aoff0 + k0, db + t * 8);
        gload_lds16(sA + aoff1 + k0, db + 4096 + t * 8);
        gload_lds16(sB + boff0 + k0, db + 8192 + t * 8);
        gload_lds16(sB + boff1 + k0, db + 12288 + t * 8);
    };

    f32x4 acc[8][4] = {};

    stage(0); stage(1); stage(2);
    asm volatile("s_waitcnt vmcnt(8)" ::: "memory");
    __builtin_amdgcn_s_barrier();

    const int fr = lane & 15;
    const int kqs = ((lane >> 4) ^ ((lane >> 1) & 3)) * 8;

    for (int j = 0; j < NT; ++j) {
        const bf16_t* bufA = lds + (j & 3) * 16384;
        const bf16_t* bufB = bufA + 8192;

        if (j + 3 < NT) stage(j + 3);

        bf16x8 a[8], b[4];
#pragma unroll
        for (int mi = 0; mi < 8; mi++)
            a[mi] = *(const bf16x8*)&bufA[(wm * 128 + mi * 16 + fr) * 32 + kqs];
#pragma unroll
        for (int ni = 0; ni < 4; ni++)
            b[ni] = *(const bf16x8*)&bufB[(wn * 64 + ni * 16 + fr) * 32 + kqs];

#pragma unroll
        for (int mi = 0; mi < 8; mi++)
#pragma unroll
            for (int ni = 0; ni < 4; ni++)
                acc[mi][ni] = mfma_bf16(a[mi], b[ni], acc[mi][ni]);

        if (j + 1 < NT) {
            if (j < NT - 3)       asm volatile("s_waitcnt vmcnt(8)" ::: "memory");
            else if (j == NT - 3) asm volatile("s_waitcnt vmcnt(4)" ::: "memory");
            else                  asm volatile("s_waitcnt vmcnt(0)" ::: "memory");
            __builtin_amdgcn_s_barrier();
        }
    }

    const int fc = lane & 15;
    const int fr4 = (lane >> 4) * 4;

    if (OUTMODE == 3) {
        const int zb = rowBase / zrows;
        const int mBase = rowBase - zb * zrows;
#pragma unroll
        for (int mi = 0; mi < 8; mi++)
#pragma unroll
            for (int ni = 0; ni < 4; ni++) {
                const int m0 = mBase + wm * 128 + mi * 16 + fr4;
                const int col = colBase + wn * 64 + ni * 16 + fc;
                bf16_t q[4];
#pragma unroll
                for (int rg = 0; rg < 4; rg++) {
                    float v = acc[mi][ni][rg];
                    if (BIAS == 1) v += bias[col];
                    q[rg] = (bf16_t)v;
                }
                const long long off = (long long)zb * strideC + (long long)col * ldc + m0;
                *(ushort4*)&((bf16_t*)C0)[off] = *(const ushort4*)q;
            }
        return;
    }

#pragma unroll
    for (int mi = 0; mi < 8; mi++)
#pragma unroll
        for (int ni = 0; ni < 4; ni++)
#pragma unroll
            for (int rg = 0; rg < 4; rg++) {
                const int row = rowBase + wm * 128 + mi * 16 + fr4 + rg;
                const int col = colBase + wn * 64 + ni * 16 + fc;
                float v = acc[mi][ni][rg];
                if (BIAS == 1) v += bias[col];
                else if (BIAS == 2) v += bias[row];
                const long long off = (long long)bz * strideC + (long long)row * ldc + col;
                if (OUTMODE == 0) {
                    ((float*)C0)[off] = v;
                } else if (OUTMODE == 1) {
                    ((bf16_t*)C0)[off] = (bf16_t)v;
                } else {
                    const bf16_t h = (bf16_t)v;
                    ((bf16_t*)C0)[off] = h;
                    ((bf16_t*)C1)[off] = (bf16_t)(v - (float)h);
                }
            }
}

// fp32 -> (hi, lo) bf16 split; n multiple of 1024; grid = n/1024 blocks of 256.
__global__ __launch_bounds__(256) void split_f32(const float* __restrict__ x,
                                                 bf16_t* __restrict__ h,
                                                 bf16_t* __restrict__ l)
{
    const long long i = ((long long)blockIdx.x * 256 + threadIdx.x) * 4;
    const float4 v = *(const float4*)&x[i];
    bf16_t hh[4], ll[4];
    const float vv[4] = {v.x, v.y, v.z, v.w};
#pragma unroll
    for (int j = 0; j < 4; j++) {
        hh[j] = (bf16_t)vv[j];
        ll[j] = (bf16_t)(vv[j] - (float)hh[j]);
    }
    *(short4*)&h[i] = *(short4*)hh;
    *(short4*)&l[i] = *(short4*)ll;
}

// fp32 -> bf16 cast; n multiple of 1024; grid = n/1024.
__global__ __launch_bounds__(256) void cast_f32(const float* __restrict__ x,
                                                bf16_t* __restrict__ y)
{
    const long long i = ((long long)blockIdx.x * 256 + threadIdx.x) * 4;
    const float4 v = *(const float4*)&x[i];
    bf16_t hh[4] = {(bf16_t)v.x, (bf16_t)v.y, (bf16_t)v.z, (bf16_t)v.w};
    *(short4*)&y[i] = *(short4*)hh;
}

// all weight conversions in one dispatch: y=0 split Wq, y=1 split Wk, y=2 cast Wv
__global__ __launch_bounds__(256) void prep_weights(
    const float* __restrict__ Wq, const float* __restrict__ Wk, const float* __restrict__ Wv,
    bf16_t* __restrict__ WqH, bf16_t* __restrict__ WqL,
    bf16_t* __restrict__ WkH, bf16_t* __restrict__ WkL, bf16_t* __restrict__ WvB)
{
    const long long i = ((long long)blockIdx.x * 256 + threadIdx.x) * 4;
    const int sel = blockIdx.y;
    const float* x = (sel == 0) ? Wq : (sel == 1) ? Wk : Wv;
    const float4 v = *(const float4*)&x[i];
    const float vv[4] = {v.x, v.y, v.z, v.w};
    bf16_t hh[4], ll[4];
#pragma unroll
    for (int j = 0; j < 4; j++) {
        hh[j] = (bf16_t)vv[j];
        ll[j] = (bf16_t)(vv[j] - (float)hh[j]);
    }
    if (sel == 0) { *(short4*)&WqH[i] = *(short4*)hh; *(short4*)&WqL[i] = *(short4*)ll; }
    else if (sel == 1) { *(short4*)&WkH[i] = *(short4*)hh; *(short4*)&WkL[i] = *(short4*)ll; }
    else { *(short4*)&WvB[i] = *(short4*)hh; }
}

// pack mask int32 [N][M] -> bit mask, 1 byte per 8 cols (row-major, M/8 B/row).
// grid = N*M/8/256 blocks of 256.
__global__ __launch_bounds__(256) void pack_mask(const int* __restrict__ mask,
                                                 unsigned char* __restrict__ mp)
{
    const long long i = (long long)blockIdx.x * 256 + threadIdx.x;   // byte index
    const int4 a = *(const int4*)&mask[i * 8];
    const int4 b = *(const int4*)&mask[i * 8 + 4];
    unsigned int v = 0;
    v |= (a.x != 0) ? 1u : 0u;  v |= (a.y != 0) ? 2u : 0u;
    v |= (a.z != 0) ? 4u : 0u;  v |= (a.w != 0) ? 8u : 0u;
    v |= (b.x != 0) ? 16u : 0u; v |= (b.y != 0) ? 32u : 0u;
    v |= (b.z != 0) ? 64u : 0u; v |= (b.w != 0) ? 128u : 0u;
    mp[i] = (unsigned char)v;
}

// Row softmax with bit-packed mask; S fp32 [rows][2048] -> P bf16 [rows][2048].
// Thread t owns 8 CONTIGUOUS cols [8t, 8t+8): 2x float4 loads, 1 byte mask,
// one 16B bf16x8 store (vectorized; was 24 scalar ops/thread).
// mask row = n0 + (r & 2047); packed row stride = 256 B.
__global__ __launch_bounds__(256) void softmax_rows(const float* __restrict__ S,
                                                    bf16_t* __restrict__ P,
                                                    const unsigned char* __restrict__ mp,
                                                    int n0)
{
    __shared__ float red[4];
    const long long r = blockIdx.x;
    const float* row = S + r * 2048;
    const int t = threadIdx.x;

    const float4 s0 = *(const float4*)&row[t * 8];
    const float4 s1 = *(const float4*)&row[t * 8 + 4];
    const unsigned int mb = mp[(long long)(n0 + (int)(r & 2047)) * 256 + t];

    float v[8] = {s0.x, s0.y, s0.z, s0.w, s1.x, s1.y, s1.z, s1.w};
#pragma unroll
    for (int i = 0; i < 8; i++) v[i] = ((mb >> i) & 1u) ? v[i] : -1000000000.0f;

    float m = v[0];
#pragma unroll
    for (int i = 1; i < 8; i++) m = fmaxf(m, v[i]);
#pragma unroll
    for (int off = 32; off; off >>= 1) m = fmaxf(m, __shfl_xor(m, off));
    if ((t & 63) == 0) red[t >> 6] = m;
    __syncthreads();
    const float rowmax = fmaxf(fmaxf(red[0], red[1]), fmaxf(red[2], red[3]));
    __syncthreads();

    float sum = 0.0f;
    float e[8];
#pragma unroll
    for (int i = 0; i < 8; i++) { e[i] = __expf(v[i] - rowmax); sum += e[i]; }
#pragma unroll
    for (int off = 32; off; off >>= 1) sum += __shfl_xor(sum, off);
    if ((t & 63) == 0) red[t >> 6] = sum;
    __syncthreads();
    const float inv = 1.0f / (red[0] + red[1] + red[2] + red[3]);

    bf16_t e8[8];
#pragma unroll
    for (int i = 0; i < 8; i++) e8[i] = (bf16_t)(e[i] * inv);
    *(bf16x8*)&P[r * 2048 + t * 8] = *(const bf16x8*)e8;
}

extern "C" void kernel_launch(void* const* d_in, const int* in_sizes, int n_in,
                              void* d_out, int out_size, void* d_ws, size_t ws_size,
                              hipStream_t stream) {
    constexpr int Bb = 8, N = 2048, M = 2048, D = 1024;
    constexpr long long MB = 1LL << 20;

    const float* querys = (const float*)d_in[0];
    const float* keys   = (const float*)d_in[1];
    const float* values = (const float*)d_in[2];
    const int*   mask   = (const int*)d_in[3];
    const float* Wq = (const float*)d_in[4];
    const float* bq = (const float*)d_in[5];
    const float* Wk = (const float*)d_in[6];
    const float* bk = (const float*)d_in[7];
    const float* Wv = (const float*)d_in[8];
    const float* bv = (const float*)d_in[9];
    float* out = (float*)d_out;

    // ---- adaptive plan ----
    // Batched: need(CB) = 11 MiB (weights + packed mask) + CB * 52 MiB
    const long long w = (long long)ws_size;
    auto needB = [&](long long cb) { return 11 * MB + cb * 52 * MB; };
    int CB = 0;
    if      (w >= needB(8)) CB = 8;
    else if (w >= needB(4)) CB = 4;
    else if (w >= needB(2)) CB = 2;
    else if (w >= needB(1)) CB = 1;
    const bool batched = (CB != 0);
    int NCH = N;
    if (!batched) {
        CB = 1;
        NCH = (w >= 39 * MB + 512 * 2048 * 6) ? 512 : 256;
    }

    char* ws = (char*)d_ws;
    long long o = 0;
    auto carve = [&](long long bytes) { char* p = ws + o; o += bytes; return p; };
    bf16_t* WqH = (bf16_t*)carve(2 * MB);
    bf16_t* WqL = (bf16_t*)carve(2 * MB);
    bf16_t* WkH = (bf16_t*)carve(2 * MB);
    bf16_t* WkL = (bf16_t*)carve(2 * MB);
    bf16_t* WvB = (bf16_t*)carve(2 * MB);
    unsigned char* MP = (unsigned char*)carve(((long long)N * M / 8 + 4095) & ~4095LL);
    bf16_t* XH  = (bf16_t*)carve((long long)CB * 4 * MB);  // also reused as V staging
    bf16_t* XL  = (bf16_t*)carve((long long)CB * 4 * MB);
    bf16_t* QH  = (bf16_t*)carve((long long)CB * 4 * MB);
    bf16_t* QL  = (bf16_t*)carve((long long)CB * 4 * MB);
    bf16_t* KH  = (bf16_t*)carve((long long)CB * 4 * MB);
    bf16_t* KL  = (bf16_t*)carve((long long)CB * 4 * MB);
    bf16_t* VT  = (bf16_t*)carve((long long)CB * 4 * MB);  // [CB][D][M]
    float*  S   = (float*)carve(batched ? (long long)CB * N * M * 4 : (long long)NCH * 2048 * 4);
    bf16_t* P   = (bf16_t*)carve(batched ? (long long)CB * N * M * 2 : (long long)NCH * 2048 * 2);

    dim3 blk(256), blkG(512);
    const long long grpElems = (long long)CB * N * D;

    // once-per-launch prep: weight conversions + mask bit-pack
    prep_weights<<<dim3((D * D) / 1024, 3), blk, 0, stream>>>(
        Wq, Wk, Wv, WqH, WqL, WkH, WkL, WvB);
    pack_mask<<<dim3((N * (long long)M / 8) / 256), blk, 0, stream>>>(mask, MP);

    for (int b0 = 0; b0 < Bb; b0 += CB) {
        const long long xoff = (long long)b0 * N * D;
        // q = xq @ Wq^T + bq -> split (rows = CB*N)
        split_f32<<<dim3(grpElems / 1024), blk, 0, stream>>>(querys + xoff, XH, XL);
        gemm256<true, 1, 2><<<dim3(D / 256, CB * N / 256, 1), blkG, 0, stream>>>(
            XH, XL, 0, D, WqH, WqL, 0, D, QH, QL, 0, D, bq, D, 1);
        // k = xk @ Wk^T + bk -> split
        split_f32<<<dim3(grpElems / 1024), blk, 0, stream>>>(keys + xoff, XH, XL);
        gemm256<true, 1, 2><<<dim3(D / 256, CB * M / 256, 1), blkG, 0, stream>>>(
            XH, XL, 0, D, WkH, WkL, 0, D, KH, KL, 0, D, bk, D, 1);
        // v = xv @ Wv^T + bv, written TRANSPOSED into VT[z][d][m]
        cast_f32<<<dim3(grpElems / 1024), blk, 0, stream>>>(values + xoff, XH);
        gemm256<false, 1, 3><<<dim3(D / 256, CB * M / 256, 1), blkG, 0, stream>>>(
            XH, nullptr, 0, D, WvB, nullptr, 0, D,
            VT, nullptr, (long long)D * M, M, bv, D, M);

        if (batched) {
            // S[z][n][m] = q[z][n] . k[z][m]  (fp32, split)
            gemm256<true, 0, 0><<<dim3(M / 256, N / 256, CB), blkG, 0, stream>>>(
                QH, QL, (long long)N * D, D,
                KH, KL, (long long)M * D, D,
                S, nullptr, (long long)N * M, M, nullptr, D, 1);
            softmax_rows<<<dim3(CB * N), blk, 0, stream>>>(S, P, MP, 0);
            // out[z][n][d] = sum_m P[z][n][m] * vT[z][d][m]
            gemm256<false, 0, 0><<<dim3(D / 256, N / 256, CB), blkG, 0, stream>>>(
                P, nullptr, (long long)N * M, M,
                VT, nullptr, (long long)D * M, M,
                out + xoff, nullptr, (long long)N * D, D, nullptr, M, 1);
        } else {
            for (int z = 0; z < CB; z++) {
                for (int n0 = 0; n0 < N; n0 += NCH) {
                    gemm256<true, 0, 0><<<dim3(M / 256, NCH / 256, 1), blkG, 0, stream>>>(
                        QH + ((long long)z * N + n0) * D, QL + ((long long)z * N + n0) * D, 0, D,
                        KH + (long long)z * M * D, KL + (long long)z * M * D, 0, D,
                        S, nullptr, 0, M, nullptr, D, 1);
                    softmax_rows<<<dim3(NCH), blk, 0, stream>>>(S, P, MP, n0);
                    gemm256<false, 0, 0><<<dim3(D / 256, NCH / 256, 1), blkG, 0, stream>>>(
                        P, nullptr, 0, M, VT + (long long)z * D * M, nullptr, 0, M,
                        out + ((long long)(b0 + z) * N + n0) * D, nullptr, 0, D, nullptr, M, 1);
                }
            }
        }
    }
    (void)in_sizes; (void)n_in; (void)out_size;
}

// Round 8
// 858.681 us; speedup vs baseline: 1.2080x; 1.1727x over previous
//
#include <hip/hip_runtime.h>
#include <cstdint>

typedef __bf16 bf16_t;
typedef __bf16 bf16x8 __attribute__((ext_vector_type(8)));
typedef float f32x4 __attribute__((ext_vector_type(4)));

#define AS1 __attribute__((address_space(1)))
#define AS3 __attribute__((address_space(3)))

__device__ __forceinline__ void gload_lds16(const bf16_t* g, bf16_t* l) {
    __builtin_amdgcn_global_load_lds((const AS1 void*)g, (AS3 void*)l, 16, 0, 0);
}
__device__ __forceinline__ f32x4 mfma_bf16(bf16x8 a, bf16x8 b, f32x4 c) {
    return __builtin_amdgcn_mfma_f32_16x16x32_bf16(a, b, c, 0, 0, 0);
}

// ---------------------------------------------------------------------------
// SPLIT GEMM, 128x128 tile, chunk-reuse schedule (round 8).
// C[r][c] = sum_k (Ah+Al)[r,k]*(Bh+Bl)[c,k] ~= Ah·Bh + Ah·Bl + Al·Bh.
// Per 32-K chunk: stage 4 panels ONCE (Ah,Al,Bh,Bl = 32 KB), then 3 MFMA
// passes over resident LDS: (a0,b0), (a0,b1), (a1,b0) -- a0/b0 fragments are
// REUSED across passes (16 ds_read + 48 MFMA per wave per chunk vs 36+48 in
// the per-term schedule; staging 8 gloads vs 12).  ONE barrier per chunk
// (48 MFMA/wave between barriers, 3x round-7).  Ring-2 chunks = 64 KB LDS
// -> 2 blocks/CU co-resident: cross-block TLP fills the vmcnt/barrier stalls
// (m114; round-1's best-total mechanism).
// LDS 16B-slot swizzle phys = slot ^ ((row>>1)&3) on BOTH sides: 0 bank
// conflicts (verified rounds 1-7).  XCD-aware bijective block swizzle.
// BIAS: 0=none, 1=+bias[col].  OUTMODE: 0 fp32; 2 split (hi->C0, lo->C1).
// ---------------------------------------------------------------------------
template <int BIAS, int OUTMODE>
__global__ __launch_bounds__(256) void gemm_sp(
    const bf16_t* __restrict__ Ah, const bf16_t* __restrict__ Al, long long strideA, int lda,
    const bf16_t* __restrict__ Bh, const bf16_t* __restrict__ Bl, long long strideB, int ldb,
    void* __restrict__ C0, void* __restrict__ C1, long long strideC, int ldc,
    const float* __restrict__ bias, int K)
{
    // slot = 16384 elements (32 KB): panels Ah@0, Al@4096, Bh@8192, Bl@12288
    __shared__ bf16_t lds[2 * 16384];

    int bx = blockIdx.x, by = blockIdx.y, bz = blockIdx.z;
    {
        const int gx = gridDim.x, gy = gridDim.y, gz = gridDim.z;
        const int n = gx * gy * gz;
        if ((n & 7) == 0) {
            int lin = bx + gx * (by + gy * bz);
            lin = (lin & 7) * (n >> 3) + (lin >> 3);
            bx = lin % gx; lin /= gx;
            by = lin % gy; bz = lin / gy;
        }
    }

    const int rowBase = by * 128;
    const int colBase = bx * 128;
    const bf16_t* AhB = Ah + (long long)bz * strideA;
    const bf16_t* BhB = Bh + (long long)bz * strideB;
    const bf16_t* AlB = Al + (long long)bz * strideA;
    const bf16_t* BlB = Bl + (long long)bz * strideB;

    const int t = threadIdx.x;
    const int lane = t & 63;
    const int w = t >> 6;
    const int wr = (w >> 1) * 64;
    const int wc = (w & 1) * 64;

    // staging: thread t covers rows r0, r0+64 at pre-swizzled 16B slot
    const int r0 = t >> 2;
    const int sl8 = ((t & 3) ^ ((r0 >> 1) & 3)) * 8;
    const long long aoff0 = (long long)(rowBase + r0) * lda + sl8;
    const long long aoff1 = (long long)(rowBase + r0 + 64) * lda + sl8;
    const long long boff0 = (long long)(colBase + r0) * ldb + sl8;
    const long long boff1 = (long long)(colBase + r0 + 64) * ldb + sl8;

    const int NC = K >> 5;

    auto stage = [&](int c) {
        bf16_t* db = lds + (c & 1) * 16384;
        const long long k0 = (long long)c * 32;
        gload_lds16(AhB + aoff0 + k0, db + t * 8);
        gload_lds16(AhB + aoff1 + k0, db + 2048 + t * 8);
        gload_lds16(AlB + aoff0 + k0, db + 4096 + t * 8);
        gload_lds16(AlB + aoff1 + k0, db + 6144 + t * 8);
        gload_lds16(BhB + boff0 + k0, db + 8192 + t * 8);
        gload_lds16(BhB + boff1 + k0, db + 10240 + t * 8);
        gload_lds16(BlB + boff0 + k0, db + 12288 + t * 8);
        gload_lds16(BlB + boff1 + k0, db + 14336 + t * 8);
    };

    f32x4 acc[4][4] = {};

    stage(0);
    asm volatile("s_waitcnt vmcnt(0)" ::: "memory");
    __builtin_amdgcn_s_barrier();

    const int fr = lane & 15;
    const int kqs = ((lane >> 4) ^ ((lane >> 1) & 3)) * 8;   // swizzled k-chunk

    for (int c = 0; c < NC; ++c) {
        const bf16_t* base = lds + (c & 1) * 16384;

        // issue next chunk's 8 panel-loads (3 MFMA passes of cover)
        if (c + 1 < NC) stage(c + 1);

        bf16x8 a0[4], a1[4], b0[4], b1[4];
#pragma unroll
        for (int mi = 0; mi < 4; mi++)
            a0[mi] = *(const bf16x8*)&base[(wr + mi * 16 + fr) * 32 + kqs];
#pragma unroll
        for (int ni = 0; ni < 4; ni++)
            b0[ni] = *(const bf16x8*)&base[8192 + (wc + ni * 16 + fr) * 32 + kqs];
        // pass 1: Ah·Bh
#pragma unroll
        for (int mi = 0; mi < 4; mi++)
#pragma unroll
            for (int ni = 0; ni < 4; ni++)
                acc[mi][ni] = mfma_bf16(a0[mi], b0[ni], acc[mi][ni]);
        // pass 2: Ah·Bl (reuse a0)
#pragma unroll
        for (int ni = 0; ni < 4; ni++)
            b1[ni] = *(const bf16x8*)&base[12288 + (wc + ni * 16 + fr) * 32 + kqs];
#pragma unroll
        for (int mi = 0; mi < 4; mi++)
#pragma unroll
            for (int ni = 0; ni < 4; ni++)
                acc[mi][ni] = mfma_bf16(a0[mi], b1[ni], acc[mi][ni]);
        // pass 3: Al·Bh (reuse b0)
#pragma unroll
        for (int mi = 0; mi < 4; mi++)
            a1[mi] = *(const bf16x8*)&base[4096 + (wr + mi * 16 + fr) * 32 + kqs];
#pragma unroll
        for (int mi = 0; mi < 4; mi++)
#pragma unroll
            for (int ni = 0; ni < 4; ni++)
                acc[mi][ni] = mfma_bf16(a1[mi], b0[ni], acc[mi][ni]);

        if (c + 1 < NC) {
            asm volatile("s_waitcnt vmcnt(0)" ::: "memory");
            __builtin_amdgcn_s_barrier();
        }
    }

    // epilogue: C/D layout col = lane&15, row = (lane>>4)*4 + reg
    const int fc = lane & 15;
    const int fr4 = (lane >> 4) * 4;
#pragma unroll
    for (int mi = 0; mi < 4; mi++)
#pragma unroll
        for (int ni = 0; ni < 4; ni++)
#pragma unroll
            for (int rg = 0; rg < 4; rg++) {
                const int row = rowBase + wr + mi * 16 + fr4 + rg;
                const int col = colBase + wc + ni * 16 + fc;
                float v = acc[mi][ni][rg];
                if (BIAS == 1) v += bias[col];
                const long long off = (long long)bz * strideC + (long long)row * ldc + col;
                if (OUTMODE == 0) {
                    ((float*)C0)[off] = v;
                } else {
                    const bf16_t h = (bf16_t)v;
                    ((bf16_t*)C0)[off] = h;
                    ((bf16_t*)C1)[off] = (bf16_t)(v - (float)h);
                }
            }
}

// ---------------------------------------------------------------------------
// Non-split 256x256-tile GEMM (V-proj, PV).  512 thr = 8 waves, 4-deep LDS
// ring, counted vmcnt(8), one barrier per tile.  Measured <=103 us (R5).
// BIAS: 0=none, 1=+bias[col].  OUTMODE: 0 fp32 -> C0;
//   3 bf16 transposed: C0[zb*strideC + col*ldc + (row%zrows)] via ushort4.
// ---------------------------------------------------------------------------
template <int BIAS, int OUTMODE>
__global__ __launch_bounds__(512, 2) void gemm256(
    const bf16_t* __restrict__ A, long long strideA, int lda,
    const bf16_t* __restrict__ B, long long strideB, int ldb,
    void* __restrict__ C0, long long strideC, int ldc,
    const float* __restrict__ bias, int K, int zrows)
{
    __shared__ bf16_t lds[4 * 16384];   // 4 ring buffers: [A 256x32 | B 256x32]

    int bx = blockIdx.x, by = blockIdx.y, bz = blockIdx.z;
    {
        const int gx = gridDim.x, gy = gridDim.y, gz = gridDim.z;
        const int n = gx * gy * gz;
        if ((n & 7) == 0) {
            int lin = bx + gx * (by + gy * bz);
            lin = (lin & 7) * (n >> 3) + (lin >> 3);
            bx = lin % gx; lin /= gx;
            by = lin % gy; bz = lin / gy;
        }
    }

    const int rowBase = by * 256;
    const int colBase = bx * 256;
    const bf16_t* AB = A + (long long)bz * strideA;
    const bf16_t* BB = B + (long long)bz * strideB;

    const int t = threadIdx.x;
    const int lane = t & 63;
    const int w = t >> 6;
    const int wm = w >> 2;
    const int wn = w & 3;

    const int r0 = t >> 2;
    const int sl8 = ((t & 3) ^ ((r0 >> 1) & 3)) * 8;
    const long long aoff0 = (long long)(rowBase + r0) * lda + sl8;
    const long long aoff1 = (long long)(rowBase + r0 + 128) * lda + sl8;
    const long long boff0 = (long long)(colBase + r0) * ldb + sl8;
    const long long boff1 = (long long)(colBase + r0 + 128) * ldb + sl8;

    const int NT = K >> 5;

    auto stage = [&](int jt) {
        const long long k0 = (long long)jt * 32;
        bf16_t* db = lds + (jt & 3) * 16384;
        gload_lds16(AB + aoff0 + k0, db + t * 8);
        gload_lds16(AB + aoff1 + k0, db + 4096 + t * 8);
        gload_lds16(BB + boff0 + k0, db + 8192 + t * 8);
        gload_lds16(BB + boff1 + k0, db + 12288 + t * 8);
    };

    f32x4 acc[8][4] = {};

    stage(0); stage(1); stage(2);
    asm volatile("s_waitcnt vmcnt(8)" ::: "memory");
    __builtin_amdgcn_s_barrier();

    const int fr = lane & 15;
    const int kqs = ((lane >> 4) ^ ((lane >> 1) & 3)) * 8;

    for (int j = 0; j < NT; ++j) {
        const bf16_t* bufA = lds + (j & 3) * 16384;
        const bf16_t* bufB = bufA + 8192;

        if (j + 3 < NT) stage(j + 3);

        bf16x8 a[8], b[4];
#pragma unroll
        for (int mi = 0; mi < 8; mi++)
            a[mi] = *(const bf16x8*)&bufA[(wm * 128 + mi * 16 + fr) * 32 + kqs];
#pragma unroll
        for (int ni = 0; ni < 4; ni++)
            b[ni] = *(const bf16x8*)&bufB[(wn * 64 + ni * 16 + fr) * 32 + kqs];

#pragma unroll
        for (int mi = 0; mi < 8; mi++)
#pragma unroll
            for (int ni = 0; ni < 4; ni++)
                acc[mi][ni] = mfma_bf16(a[mi], b[ni], acc[mi][ni]);

        if (j + 1 < NT) {
            if (j < NT - 3)       asm volatile("s_waitcnt vmcnt(8)" ::: "memory");
            else if (j == NT - 3) asm volatile("s_waitcnt vmcnt(4)" ::: "memory");
            else                  asm volatile("s_waitcnt vmcnt(0)" ::: "memory");
            __builtin_amdgcn_s_barrier();
        }
    }

    const int fc = lane & 15;
    const int fr4 = (lane >> 4) * 4;

    if (OUTMODE == 3) {
        const int zb = rowBase / zrows;
        const int mBase = rowBase - zb * zrows;
#pragma unroll
        for (int mi = 0; mi < 8; mi++)
#pragma unroll
            for (int ni = 0; ni < 4; ni++) {
                const int m0 = mBase + wm * 128 + mi * 16 + fr4;
                const int col = colBase + wn * 64 + ni * 16 + fc;
                bf16_t q[4];
#pragma unroll
                for (int rg = 0; rg < 4; rg++) {
                    float v = acc[mi][ni][rg];
                    if (BIAS == 1) v += bias[col];
                    q[rg] = (bf16_t)v;
                }
                const long long off = (long long)zb * strideC + (long long)col * ldc + m0;
                *(ushort4*)&((bf16_t*)C0)[off] = *(const ushort4*)q;
            }
        return;
    }

#pragma unroll
    for (int mi = 0; mi < 8; mi++)
#pragma unroll
        for (int ni = 0; ni < 4; ni++)
#pragma unroll
            for (int rg = 0; rg < 4; rg++) {
                const int row = rowBase + wm * 128 + mi * 16 + fr4 + rg;
                const int col = colBase + wn * 64 + ni * 16 + fc;
                float v = acc[mi][ni][rg];
                if (BIAS == 1) v += bias[col];
                const long long off = (long long)bz * strideC + (long long)row * ldc + col;
                ((float*)C0)[off] = v;
            }
}

// fp32 -> (hi, lo) bf16 split; n multiple of 1024; grid = n/1024 blocks of 256.
__global__ __launch_bounds__(256) void split_f32(const float* __restrict__ x,
                                                 bf16_t* __restrict__ h,
                                                 bf16_t* __restrict__ l)
{
    const long long i = ((long long)blockIdx.x * 256 + threadIdx.x) * 4;
    const float4 v = *(const float4*)&x[i];
    bf16_t hh[4], ll[4];
    const float vv[4] = {v.x, v.y, v.z, v.w};
#pragma unroll
    for (int j = 0; j < 4; j++) {
        hh[j] = (bf16_t)vv[j];
        ll[j] = (bf16_t)(vv[j] - (float)hh[j]);
    }
    *(short4*)&h[i] = *(short4*)hh;
    *(short4*)&l[i] = *(short4*)ll;
}

// fp32 -> bf16 cast; n multiple of 1024; grid = n/1024.
__global__ __launch_bounds__(256) void cast_f32(const float* __restrict__ x,
                                                bf16_t* __restrict__ y)
{
    const long long i = ((long long)blockIdx.x * 256 + threadIdx.x) * 4;
    const float4 v = *(const float4*)&x[i];
    bf16_t hh[4] = {(bf16_t)v.x, (bf16_t)v.y, (bf16_t)v.z, (bf16_t)v.w};
    *(short4*)&y[i] = *(short4*)hh;
}

// all weight conversions in one dispatch: y=0 split Wq, y=1 split Wk, y=2 cast Wv
__global__ __launch_bounds__(256) void prep_weights(
    const float* __restrict__ Wq, const float* __restrict__ Wk, const float* __restrict__ Wv,
    bf16_t* __restrict__ WqH, bf16_t* __restrict__ WqL,
    bf16_t* __restrict__ WkH, bf16_t* __restrict__ WkL, bf16_t* __restrict__ WvB)
{
    const long long i = ((long long)blockIdx.x * 256 + threadIdx.x) * 4;
    const int sel = blockIdx.y;
    const float* x = (sel == 0) ? Wq : (sel == 1) ? Wk : Wv;
    const float4 v = *(const float4*)&x[i];
    const float vv[4] = {v.x, v.y, v.z, v.w};
    bf16_t hh[4], ll[4];
#pragma unroll
    for (int j = 0; j < 4; j++) {
        hh[j] = (bf16_t)vv[j];
        ll[j] = (bf16_t)(vv[j] - (float)hh[j]);
    }
    if (sel == 0) { *(short4*)&WqH[i] = *(short4*)hh; *(short4*)&WqL[i] = *(short4*)ll; }
    else if (sel == 1) { *(short4*)&WkH[i] = *(short4*)hh; *(short4*)&WkL[i] = *(short4*)ll; }
    else { *(short4*)&WvB[i] = *(short4*)hh; }
}

// pack mask int32 [N][M] -> bit mask, 1 byte per 8 cols (row-major, M/8 B/row).
__global__ __launch_bounds__(256) void pack_mask(const int* __restrict__ mask,
                                                 unsigned char* __restrict__ mp)
{
    const long long i = (long long)blockIdx.x * 256 + threadIdx.x;   // byte index
    const int4 a = *(const int4*)&mask[i * 8];
    const int4 b = *(const int4*)&mask[i * 8 + 4];
    unsigned int v = 0;
    v |= (a.x != 0) ? 1u : 0u;  v |= (a.y != 0) ? 2u : 0u;
    v |= (a.z != 0) ? 4u : 0u;  v |= (a.w != 0) ? 8u : 0u;
    v |= (b.x != 0) ? 16u : 0u; v |= (b.y != 0) ? 32u : 0u;
    v |= (b.z != 0) ? 64u : 0u; v |= (b.w != 0) ? 128u : 0u;
    mp[i] = (unsigned char)v;
}

// Row softmax with bit-packed mask; S fp32 [rows][2048] -> P bf16 [rows][2048].
// Thread t owns 8 contiguous cols; mask row = n0 + (r & 2047); packed stride 256 B.
__global__ __launch_bounds__(256) void softmax_rows(const float* __restrict__ S,
                                                    bf16_t* __restrict__ P,
                                                    const unsigned char* __restrict__ mp,
                                                    int n0)
{
    __shared__ float red[4];
    const long long r = blockIdx.x;
    const float* row = S + r * 2048;
    const int t = threadIdx.x;

    const float4 s0 = *(const float4*)&row[t * 8];
    const float4 s1 = *(const float4*)&row[t * 8 + 4];
    const unsigned int mb = mp[(long long)(n0 + (int)(r & 2047)) * 256 + t];

    float v[8] = {s0.x, s0.y, s0.z, s0.w, s1.x, s1.y, s1.z, s1.w};
#pragma unroll
    for (int i = 0; i < 8; i++) v[i] = ((mb >> i) & 1u) ? v[i] : -1000000000.0f;

    float m = v[0];
#pragma unroll
    for (int i = 1; i < 8; i++) m = fmaxf(m, v[i]);
#pragma unroll
    for (int off = 32; off; off >>= 1) m = fmaxf(m, __shfl_xor(m, off));
    if ((t & 63) == 0) red[t >> 6] = m;
    __syncthreads();
    const float rowmax = fmaxf(fmaxf(red[0], red[1]), fmaxf(red[2], red[3]));
    __syncthreads();

    float sum = 0.0f;
    float e[8];
#pragma unroll
    for (int i = 0; i < 8; i++) { e[i] = __expf(v[i] - rowmax); sum += e[i]; }
#pragma unroll
    for (int off = 32; off; off >>= 1) sum += __shfl_xor(sum, off);
    if ((t & 63) == 0) red[t >> 6] = sum;
    __syncthreads();
    const float inv = 1.0f / (red[0] + red[1] + red[2] + red[3]);

    bf16_t e8[8];
#pragma unroll
    for (int i = 0; i < 8; i++) e8[i] = (bf16_t)(e[i] * inv);
    *(bf16x8*)&P[r * 2048 + t * 8] = *(const bf16x8*)e8;
}

extern "C" void kernel_launch(void* const* d_in, const int* in_sizes, int n_in,
                              void* d_out, int out_size, void* d_ws, size_t ws_size,
                              hipStream_t stream) {
    constexpr int Bb = 8, N = 2048, M = 2048, D = 1024;
    constexpr long long MB = 1LL << 20;

    const float* querys = (const float*)d_in[0];
    const float* keys   = (const float*)d_in[1];
    const float* values = (const float*)d_in[2];
    const int*   mask   = (const int*)d_in[3];
    const float* Wq = (const float*)d_in[4];
    const float* bq = (const float*)d_in[5];
    const float* Wk = (const float*)d_in[6];
    const float* bk = (const float*)d_in[7];
    const float* Wv = (const float*)d_in[8];
    const float* bv = (const float*)d_in[9];
    float* out = (float*)d_out;

    // ---- adaptive plan ----
    const long long w = (long long)ws_size;
    auto needB = [&](long long cb) { return 11 * MB + cb * 52 * MB; };
    int CB = 0;
    if      (w >= needB(8)) CB = 8;
    else if (w >= needB(4)) CB = 4;
    else if (w >= needB(2)) CB = 2;
    else if (w >= needB(1)) CB = 1;
    const bool batched = (CB != 0);
    int NCH = N;
    if (!batched) {
        CB = 1;
        NCH = (w >= 39 * MB + 512 * 2048 * 6) ? 512 : 256;
    }

    char* ws = (char*)d_ws;
    long long o = 0;
    auto carve = [&](long long bytes) { char* p = ws + o; o += bytes; return p; };
    bf16_t* WqH = (bf16_t*)carve(2 * MB);
    bf16_t* WqL = (bf16_t*)carve(2 * MB);
    bf16_t* WkH = (bf16_t*)carve(2 * MB);
    bf16_t* WkL = (bf16_t*)carve(2 * MB);
    bf16_t* WvB = (bf16_t*)carve(2 * MB);
    unsigned char* MP = (unsigned char*)carve(((long long)N * M / 8 + 4095) & ~4095LL);
    bf16_t* XH  = (bf16_t*)carve((long long)CB * 4 * MB);  // also reused as V staging
    bf16_t* XL  = (bf16_t*)carve((long long)CB * 4 * MB);
    bf16_t* QH  = (bf16_t*)carve((long long)CB * 4 * MB);
    bf16_t* QL  = (bf16_t*)carve((long long)CB * 4 * MB);
    bf16_t* KH  = (bf16_t*)carve((long long)CB * 4 * MB);
    bf16_t* KL  = (bf16_t*)carve((long long)CB * 4 * MB);
    bf16_t* VT  = (bf16_t*)carve((long long)CB * 4 * MB);  // [CB][D][M]
    float*  S   = (float*)carve(batched ? (long long)CB * N * M * 4 : (long long)NCH * 2048 * 4);
    bf16_t* P   = (bf16_t*)carve(batched ? (long long)CB * N * M * 2 : (long long)NCH * 2048 * 2);

    dim3 blk(256), blkG(512);
    const long long grpElems = (long long)CB * N * D;

    // once-per-launch prep: weight conversions + mask bit-pack
    prep_weights<<<dim3((D * D) / 1024, 3), blk, 0, stream>>>(
        Wq, Wk, Wv, WqH, WqL, WkH, WkL, WvB);
    pack_mask<<<dim3((N * (long long)M / 8) / 256), blk, 0, stream>>>(mask, MP);

    for (int b0 = 0; b0 < Bb; b0 += CB) {
        const long long xoff = (long long)b0 * N * D;
        // q = xq @ Wq^T + bq -> split (rows = CB*N)  [chunk-reuse split kernel]
        split_f32<<<dim3(grpElems / 1024), blk, 0, stream>>>(querys + xoff, XH, XL);
        gemm_sp<1, 2><<<dim3(D / 128, CB * N / 128, 1), blk, 0, stream>>>(
            XH, XL, 0, D, WqH, WqL, 0, D, QH, QL, 0, D, bq, D);
        // k = xk @ Wk^T + bk -> split
        split_f32<<<dim3(grpElems / 1024), blk, 0, stream>>>(keys + xoff, XH, XL);
        gemm_sp<1, 2><<<dim3(D / 128, CB * M / 128, 1), blk, 0, stream>>>(
            XH, XL, 0, D, WkH, WkL, 0, D, KH, KL, 0, D, bk, D);
        // v = xv @ Wv^T + bv, written TRANSPOSED into VT[z][d][m]
        cast_f32<<<dim3(grpElems / 1024), blk, 0, stream>>>(values + xoff, XH);
        gemm256<1, 3><<<dim3(D / 256, CB * M / 256, 1), blkG, 0, stream>>>(
            XH, 0, D, WvB, 0, D,
            VT, (long long)D * M, M, bv, D, M);

        if (batched) {
            // S[z][n][m] = q[z][n] . k[z][m]  (fp32, split; 2 blocks/CU)
            gemm_sp<0, 0><<<dim3(M / 128, N / 128, CB), blk, 0, stream>>>(
                QH, QL, (long long)N * D, D,
                KH, KL, (long long)M * D, D,
                S, nullptr, (long long)N * M, M, nullptr, D);
            softmax_rows<<<dim3(CB * N), blk, 0, stream>>>(S, P, MP, 0);
            // out[z][n][d] = sum_m P[z][n][m] * vT[z][d][m]
            gemm256<0, 0><<<dim3(D / 256, N / 256, CB), blkG, 0, stream>>>(
                P, (long long)N * M, M,
                VT, (long long)D * M, M,
                out + xoff, (long long)N * D, D, nullptr, M, 1);
        } else {
            for (int z = 0; z < CB; z++) {
                for (int n0 = 0; n0 < N; n0 += NCH) {
                    gemm_sp<0, 0><<<dim3(M / 128, NCH / 128, 1), blk, 0, stream>>>(
                        QH + ((long long)z * N + n0) * D, QL + ((long long)z * N + n0) * D, 0, D,
                        KH + (long long)z * M * D, KL + (long long)z * M * D, 0, D,
                        S, nullptr, 0, M, nullptr, D);
                    softmax_rows<<<dim3(NCH), blk, 0, stream>>>(S, P, MP, n0);
                    gemm256<0, 0><<<dim3(D / 256, NCH / 256, 1), blkG, 0, stream>>>(
                        P, 0, M, VT + (long long)z * D * M, 0, M,
                        out + ((long long)(b0 + z) * N + n0) * D, 0, D, nullptr, M, 1);
                }
            }
        }
    }
    (void)in_sizes; (void)n_in; (void)out_size;
}